// Round 4
// baseline (3517.482 us; speedup 1.0000x reference)
//
#include <hip/hip_runtime.h>
#include <math.h>

typedef _Float16 f16x8 __attribute__((ext_vector_type(8)));
typedef float    f32x4 __attribute__((ext_vector_type(4)));
typedef _Float16 half2v __attribute__((ext_vector_type(2)));

#define TT   2048
#define ROWB 640      // bytes per H' row (320 f16 slots; 288 used; stride mult of 128 keeps XOR in-row)

// W'' layout (rows 0..513, cols 0..287):
//   r<512,  k<256   : w_hh[r][k]
//   r<512,  256..261: w_ih[r][k-256]   (feat order: i, q, amp, amp3, sin, cos)
//   r<512,  k==262  : b_ih[r]+b_hh[r]
//   r 512/513, k<256: fc_w[r-512][k];  k==262: fc_b[r-512];  else 0
// H'[c][k]: k<256: h_{t-1}[k] (f16); 256..261: feats(x[t]); 262: 1.0; else 0.

__global__ __launch_bounds__(512, 2)
void janet_mfma(const float* __restrict__ x,
                const float* __restrict__ w_ih,
                const float* __restrict__ w_hh,
                const float* __restrict__ b_ih,
                const float* __restrict__ b_hh,
                const float* __restrict__ fc_w,
                const float* __restrict__ fc_b,
                float* __restrict__ out)
{
    __shared__ __align__(16) unsigned char Hb[2][16][ROWB];  // ping-pong H', XOR-swizzled 16B blocks
    __shared__ float pout[2][8][16][2];                      // out-projection partials [buf][wave][c][o]

    const int tid  = threadIdx.x;
    const int wid  = tid >> 6;          // 8 waves
    const int lane = tid & 63;
    const int c    = lane & 15;         // batch column
    const int hi   = lane >> 4;         // k-quarter
    const int swz  = (c & 7) << 4;      // 16B-block XOR swizzle
    const int b0   = blockIdx.x * 16;

    // ---------------- LDS init ----------------
    for (int i = tid; i < (2 * 16 * ROWB) / 4; i += 512) ((unsigned int*)Hb)[i] = 0u;
    ((float*)pout)[tid] = 0.f;          // 512 floats
    __syncthreads();
    if (tid < 32) {                     // H'[c][262] = 1.0h (both buffers)
        const int p = tid >> 4, cc = tid & 15;
        const int sz = (cc & 7) << 4;
        *(unsigned short*)((unsigned char*)&Hb[p][cc][0] + (524 ^ sz)) = 0x3C00;
    }

    // ---------------- A-fragments (register/AGPR resident) ----------------
    // lane slot (l, j) of slice s holds W''[row(l)][s*32 + hi*8 + j]; rows: l&15 within tile.
    auto wval = [&](int r, int k) -> float {
        if (r < 512) {
            if (k < 256) return w_hh[r * 256 + k];
            if (k < 262) return w_ih[r * 6 + (k - 256)];
            if (k == 262) return b_ih[r] + b_hh[r];
            return 0.f;
        } else if (r < 514) {
            const int o = r - 512;
            if (k < 256) return fc_w[o * 256 + k];
            if (k == 262) return fc_b[o];
            return 0.f;
        }
        return 0.f;
    };

    const int mt[4] = {2 * wid, 2 * wid + 1, 2 * wid + 16, 2 * wid + 17}; // f0,f1,g0,g1 tiles
    f16x8 A[4][9];
    #pragma unroll
    for (int i = 0; i < 4; ++i) {
        const int r = 16 * mt[i] + c;
        #pragma unroll
        for (int s = 0; s < 8; ++s) {   // bulk: contiguous w_hh
            const float4 v0 = *reinterpret_cast<const float4*>(&w_hh[r * 256 + s * 32 + hi * 8]);
            const float4 v1 = *reinterpret_cast<const float4*>(&w_hh[r * 256 + s * 32 + hi * 8 + 4]);
            f16x8 a;
            a[0]=(_Float16)v0.x; a[1]=(_Float16)v0.y; a[2]=(_Float16)v0.z; a[3]=(_Float16)v0.w;
            a[4]=(_Float16)v1.x; a[5]=(_Float16)v1.y; a[6]=(_Float16)v1.z; a[7]=(_Float16)v1.w;
            A[i][s] = a;
        }
        {   // slice 8: feats cols + bias
            f16x8 a;
            #pragma unroll
            for (int j = 0; j < 8; ++j) a[j] = (_Float16)wval(r, 256 + hi * 8 + j);
            A[i][8] = a;
        }
    }
    f16x8 Aout, Aout8;   // out-tile (rows 512..527; only 512/513 nonzero) — slice wid (+ slice 8 on wave 0)
    #pragma unroll
    for (int j = 0; j < 8; ++j) Aout[j] = (_Float16)wval(512 + c, wid * 32 + hi * 8 + j);
    #pragma unroll
    for (int j = 0; j < 8; ++j) Aout8[j] = (_Float16)wval(512 + c, 256 + hi * 8 + j);

    float hold[2][4] = {{0.f,0.f,0.f,0.f},{0.f,0.f,0.f,0.f}};  // own h elements (f32)

    const float* xb = x + ((size_t)(b0 + c)) * TT * 2;   // this lane's batch stream (lanes c)

    __syncthreads();
    // feats(x[0]) -> Hb[1] ext  (step 0 reads Hb[1])
    if (wid == 0 && lane < 16) {
        const float2 xv = *reinterpret_cast<const float2*>(xb + 0);
        const float amp = sqrtf(xv.x * xv.x + xv.y * xv.y);
        unsigned char* dst = (unsigned char*)&Hb[1][lane][0];
        half2v f01; f01.x = (_Float16)xv.x;        f01.y = (_Float16)xv.y;
        half2v f23; f23.x = (_Float16)amp;         f23.y = (_Float16)(amp*amp*amp);
        half2v f45; f45.x = (_Float16)(xv.y/amp);  f45.y = (_Float16)(xv.x/amp);
        *(unsigned int*)(dst + (512 ^ swz)) = __builtin_bit_cast(unsigned int, f01);
        *(unsigned int*)(dst + (516 ^ swz)) = __builtin_bit_cast(unsigned int, f23);
        *(unsigned int*)(dst + (520 ^ swz)) = __builtin_bit_cast(unsigned int, f45);
    }
    __syncthreads();

    #pragma unroll 1
    for (int t = 0; t <= TT; ++t) {
        const int p_read  = (t + 1) & 1;   // holds h_{t-1} + feats(x[t])
        const int p_write = t & 1;

        // prefetch x[t+1] (wave 0 lanes 0..15), consumed at end of this iteration
        float2 xv;
        if (wid == 0 && lane < 16 && t + 1 < TT)
            xv = *reinterpret_cast<const float2*>(xb + 2 * (t + 1));

        // ---- MFMA: 9 K-slices; B-frag lane slot (l,j) = H'[c][s*32+hi*8+j] ----
        const unsigned char* hrow = (const unsigned char*)&Hb[p_read][c][0];
        f32x4 C0 = {0,0,0,0}, C1 = {0,0,0,0}, C2 = {0,0,0,0}, C3 = {0,0,0,0};
        f32x4 Cout = {0,0,0,0};
        const int doMain = (t < TT);
        #pragma unroll
        for (int s = 0; s < 9; ++s) {
            const f16x8 Bs = *(const f16x8*)(hrow + ((s * 64 + hi * 16) ^ swz));
            if (doMain) {
                C0 = __builtin_amdgcn_mfma_f32_16x16x32_f16(A[0][s], Bs, C0, 0, 0, 0);
                C1 = __builtin_amdgcn_mfma_f32_16x16x32_f16(A[1][s], Bs, C1, 0, 0, 0);
                C2 = __builtin_amdgcn_mfma_f32_16x16x32_f16(A[2][s], Bs, C2, 0, 0, 0);
                C3 = __builtin_amdgcn_mfma_f32_16x16x32_f16(A[3][s], Bs, C3, 0, 0, 0);
            }
            if (s == wid)
                Cout = __builtin_amdgcn_mfma_f32_16x16x32_f16(Aout, Bs, Cout, 0, 0, 0);
            if (wid == 0 && s == 8)
                Cout = __builtin_amdgcn_mfma_f32_16x16x32_f16(Aout8, Bs, Cout, 0, 0, 0);
        }

        // ---- gates + h update + h write (rows 16*mt + 4*hi + reg, col c) ----
        if (doMain) {
            unsigned char* dstrow = (unsigned char*)&Hb[p_write][c][0];
            #pragma unroll
            for (int pp = 0; pp < 2; ++pp) {
                const f32x4 f = (pp == 0) ? C0 : C1;
                const f32x4 g = (pp == 0) ? C2 : C3;
                float hn[4];
                #pragma unroll
                for (int r = 0; r < 4; ++r) {
                    const float gf = 1.0f / (1.0f + __expf(-f[r]));
                    const float gg = 1.0f / (1.0f + __expf(-g[r]));
                    hn[r] = gg + gf * (hold[pp][r] - gg);
                    hold[pp][r] = hn[r];
                }
                half2v lo; lo.x = (_Float16)hn[0]; lo.y = (_Float16)hn[1];
                half2v hp; hp.x = (_Float16)hn[2]; hp.y = (_Float16)hn[3];
                uint2 v; v.x = __builtin_bit_cast(unsigned int, lo);
                         v.y = __builtin_bit_cast(unsigned int, hp);
                const int r0 = 16 * mt[pp] + hi * 4;
                *(uint2*)(dstrow + ((2 * r0) ^ swz)) = v;
            }
        }

        // ---- feats(x[t+1]) -> Hb[p_write] ext ----
        if (wid == 0 && lane < 16 && t + 1 < TT) {
            const float amp = sqrtf(xv.x * xv.x + xv.y * xv.y);
            unsigned char* dst = (unsigned char*)&Hb[p_write][lane][0];
            half2v f01; f01.x = (_Float16)xv.x;        f01.y = (_Float16)xv.y;
            half2v f23; f23.x = (_Float16)amp;         f23.y = (_Float16)(amp*amp*amp);
            half2v f45; f45.x = (_Float16)(xv.y/amp);  f45.y = (_Float16)(xv.x/amp);
            *(unsigned int*)(dst + (512 ^ swz)) = __builtin_bit_cast(unsigned int, f01);
            *(unsigned int*)(dst + (516 ^ swz)) = __builtin_bit_cast(unsigned int, f23);
            *(unsigned int*)(dst + (520 ^ swz)) = __builtin_bit_cast(unsigned int, f45);
        }

        // ---- out-projection partial (rows 512(o0)/513(o1) live in reg 0/1 of hi==0 lanes) ----
        if (hi == 0) {
            float2 po; po.x = Cout[0]; po.y = Cout[1];
            *(float2*)&pout[p_read][wid][c][0] = po;
        }
        // ---- reduce out[t-2] (written into pout[t&1] during step t-1) ----
        if (wid == 1 && lane < 16 && t >= 2) {
            float s0 = 0.f, s1 = 0.f;
            #pragma unroll
            for (int w = 0; w < 8; ++w) {
                s0 += pout[p_write][w][lane][0];
                s1 += pout[p_write][w][lane][1];
            }
            *reinterpret_cast<float2*>(out + ((size_t)(b0 + lane) * TT + (t - 2)) * 2) =
                make_float2(s0, s1);
        }
        __syncthreads();
    }

    // epilogue: out[TT-1] partials were written during t==TT into pout[(TT+1)&1]
    if (wid == 1 && lane < 16) {
        float s0 = 0.f, s1 = 0.f;
        #pragma unroll
        for (int w = 0; w < 8; ++w) {
            s0 += pout[(TT + 1) & 1][w][lane][0];
            s1 += pout[(TT + 1) & 1][w][lane][1];
        }
        *reinterpret_cast<float2*>(out + ((size_t)(b0 + lane) * TT + (TT - 1)) * 2) =
            make_float2(s0, s1);
    }
}

extern "C" void kernel_launch(void* const* d_in, const int* in_sizes, int n_in,
                              void* d_out, int out_size, void* d_ws, size_t ws_size,
                              hipStream_t stream) {
    (void)in_sizes; (void)n_in; (void)out_size; (void)d_ws; (void)ws_size;
    const float* x    = (const float*)d_in[0];
    // d_in[1] = h_0 : reference ignores it (uses zeros)
    const float* w_ih = (const float*)d_in[2];
    const float* w_hh = (const float*)d_in[3];
    const float* b_ih = (const float*)d_in[4];
    const float* b_hh = (const float*)d_in[5];
    const float* fc_w = (const float*)d_in[6];
    const float* fc_b = (const float*)d_in[7];
    float* outp = (float*)d_out;

    hipLaunchKernelGGL(janet_mfma, dim3(4), dim3(512), 0, stream,
                       x, w_ih, w_hh, b_ih, b_hh, fc_w, fc_b, outp);
}